// Round 1
// baseline (826.898 us; speedup 1.0000x reference)
//
#include <hip/hip_runtime.h>

#define EMB_DIM 128
#define NEG 5

// One half-wave (32 lanes) per batch element. Each lane loads a float4
// (16 B) of the 128-float row -> one coalesced 512 B transaction per row.
// 4 waves/block * 2 elems/wave = 8 elements per 256-thread block.
__global__ __launch_bounds__(256) void skipgram_loss_kernel(
    const float* __restrict__ u_weight,
    const float* __restrict__ v_weight,
    const int*   __restrict__ pos_u,
    const int*   __restrict__ pos_v,
    const int*   __restrict__ neg_v,
    float* __restrict__ out,
    int B, float inv_b)
{
    __shared__ float blocksum;
    if (threadIdx.x == 0) blocksum = 0.0f;
    __syncthreads();

    const int lane        = threadIdx.x & 63;
    const int sub         = lane & 31;        // lane within half-wave
    const int half        = lane >> 5;        // which half-wave
    const int waveInBlock = threadIdx.x >> 6; // 0..3

    const int b = blockIdx.x * 8 + waveInBlock * 2 + half;

    float loss = 0.0f;
    if (b < B) {
        const int pu = pos_u[b];
        const int pv = pos_v[b];

        // Load all gather indices up-front so the float4 loads can all be
        // in flight before any reduce.
        int nidx[NEG];
        #pragma unroll
        for (int k = 0; k < NEG; ++k) nidx[k] = neg_v[b * NEG + k];

        const float4 u4 = ((const float4*)(u_weight + (size_t)pu * EMB_DIM))[sub];
        const float4 v4 = ((const float4*)(v_weight + (size_t)pv * EMB_DIM))[sub];
        float4 n4[NEG];
        #pragma unroll
        for (int k = 0; k < NEG; ++k)
            n4[k] = ((const float4*)(v_weight + (size_t)nidx[k] * EMB_DIM))[sub];

        // positive score
        float dot = u4.x * v4.x + u4.y * v4.y + u4.z * v4.z + u4.w * v4.w;
        #pragma unroll
        for (int m = 16; m >= 1; m >>= 1)
            dot += __shfl_xor(dot, m, 64);
        float score = fminf(fmaxf(dot, -10.0f), 10.0f);
        loss = log1pf(__expf(-score));  // -log_sigmoid(score)

        // negative scores
        #pragma unroll
        for (int k = 0; k < NEG; ++k) {
            float nd = u4.x * n4[k].x + u4.y * n4[k].y + u4.z * n4[k].z + u4.w * n4[k].w;
            #pragma unroll
            for (int m = 16; m >= 1; m >>= 1)
                nd += __shfl_xor(nd, m, 64);
            float ns = fminf(fmaxf(nd, -10.0f), 10.0f);
            loss += log1pf(__expf(ns)); // -log_sigmoid(-ns)
        }
    }

    // one lane per half-wave contributes
    if (sub == 0) atomicAdd(&blocksum, loss);
    __syncthreads();
    if (threadIdx.x == 0) atomicAdd(out, blocksum * inv_b);
}

extern "C" void kernel_launch(void* const* d_in, const int* in_sizes, int n_in,
                              void* d_out, int out_size, void* d_ws, size_t ws_size,
                              hipStream_t stream) {
    const float* u_weight = (const float*)d_in[0];
    const float* v_weight = (const float*)d_in[1];
    const int*   pos_u    = (const int*)d_in[2];
    const int*   pos_v    = (const int*)d_in[3];
    const int*   neg_v    = (const int*)d_in[4];
    float* out = (float*)d_out;

    const int B = in_sizes[2];

    // d_out is poisoned to 0xAA before every timed replay -> zero it first.
    hipMemsetAsync(out, 0, sizeof(float), stream);

    const int blocks = (B + 7) / 8; // 8 elements per 256-thread block
    skipgram_loss_kernel<<<blocks, 256, 0, stream>>>(
        u_weight, v_weight, pos_u, pos_v, neg_v, out, B, 1.0f / (float)B);
}